// Round 2
// baseline (666.707 us; speedup 1.0000x reference)
//
#include <hip/hip_runtime.h>

#define BB 8
#define NN 8192
#define SS 2048
#define CC 256
#define KNN 8
#define TOPM 10   // phase-1 candidate count (top-8 + safety margin for f32 error)

// ---------------- Kernel A: per-thread-query top-8 KNN + IDW weights --------
// Phase 1: f32 diff-form distances, keep top-10 (insertion, sorted ascending).
// Phase 2: recompute the 10 in f64 (exact ranking vs the f64 np reference),
//          sort by (dist, idx), keep smallest 8.
__global__ __launch_bounds__(256) void knn_kernel(
    const float* __restrict__ xyz,   // [B,3,N]
    const float* __restrict__ sxyz,  // [B,3,S]
    int*   __restrict__ out_idx,     // [B,N,8]
    float* __restrict__ out_w)       // [B,N,8]
{
    __shared__ float4 sp[SS];        // 32 KB: x,y,z,(pad)
    const int b     = blockIdx.x >> 5;   // 32 blocks per batch
    const int chunk = blockIdx.x & 31;
    const int tid   = threadIdx.x;

    const float* sb = sxyz + (long)b * 3 * SS;
#pragma unroll
    for (int i = 0; i < SS / 256; ++i) {
        int s = tid + i * 256;
        sp[s] = make_float4(sb[s], sb[SS + s], sb[2 * SS + s], 0.f);
    }
    __syncthreads();

    const int n = chunk * 256 + tid;
    const float* xb = xyz + (long)b * 3 * NN;
    const float qx = xb[n], qy = xb[NN + n], qz = xb[2 * NN + n];

    float d[TOPM];
    int   id[TOPM];
#pragma unroll
    for (int j = 0; j < TOPM; ++j) { d[j] = 3.4e38f; id[j] = 0; }

    for (int s = 0; s < SS; ++s) {
        float4 p = sp[s];             // wave-uniform addr -> LDS broadcast
        float dx = p.x - qx, dy = p.y - qy, dz = p.z - qz;
        float dist = fmaf(dx, dx, fmaf(dy, dy, dz * dz));
        if (dist < d[TOPM - 1]) {
            float cd = dist; int ci = s;
#pragma unroll
            for (int j = 0; j < TOPM; ++j) {
                bool sw = cd < d[j];
                float td = sw ? d[j] : cd;
                float nd = sw ? cd   : d[j];
                int   ti = sw ? id[j] : ci;
                int   ni = sw ? ci    : id[j];
                d[j] = nd; id[j] = ni; cd = td; ci = ti;
            }
        }
    }

    // ---- Phase 2: f64 re-rank of the 10 candidates ----
    double dd[TOPM];
    const double qdx = (double)qx, qdy = (double)qy, qdz = (double)qz;
#pragma unroll
    for (int j = 0; j < TOPM; ++j) {
        float4 p = sp[id[j]];
        double ex = (double)p.x - qdx;
        double ey = (double)p.y - qdy;
        double ez = (double)p.z - qdz;
        dd[j] = ex * ex + ey * ey + ez * ez;
    }
    // bubble sorting network on (dd, id), static indices only
#define CE(i, j)                                                        \
    {                                                                   \
        bool sw = (dd[j] < dd[i]) || (dd[j] == dd[i] && id[j] < id[i]); \
        double t0 = sw ? dd[j] : dd[i];                                 \
        double t1 = sw ? dd[i] : dd[j];                                 \
        int    u0 = sw ? id[j] : id[i];                                 \
        int    u1 = sw ? id[i] : id[j];                                 \
        dd[i] = t0; dd[j] = t1; id[i] = u0; id[j] = u1;                 \
    }
#pragma unroll
    for (int pass = 0; pass < TOPM - 1; ++pass) {
        CE(0,1) CE(1,2) CE(2,3) CE(3,4) CE(4,5) CE(5,6) CE(6,7) CE(7,8) CE(8,9)
    }
#undef CE

    // weights: diff-form distance exactly like reference epilogue (f32)
    float inv[KNN];
    float ssum = 0.f;
#pragma unroll
    for (int k = 0; k < KNN; ++k) {
        float4 p = sp[id[k]];
        float dx = p.x - qx, dy = p.y - qy, dz = p.z - qz;
        float dv = sqrtf(dx * dx + dy * dy + dz * dz);
        dv = fmaxf(dv, 1e-10f);
        inv[k] = 1.0f / dv;
        ssum += inv[k];
    }
    const float rs = 1.0f / ssum;
    const long base = ((long)b * NN + n) * KNN;
#pragma unroll
    for (int k = 0; k < KNN; ++k) {
        out_idx[base + k] = id[k];
        out_w[base + k]   = inv[k] * rs;
    }
}

// ---------------- Kernel B: sparse_feat [B,C,S] -> [B,S,C] ------------------
__global__ __launch_bounds__(256) void transpose_kernel(
    const float* __restrict__ sf,   // [B,C,S]
    float* __restrict__ sfT)        // [B,S,C]
{
    __shared__ float tile[32][33];
    const int b  = blockIdx.z;
    const int c0 = blockIdx.y * 32;
    const int s0 = blockIdx.x * 32;
    const int tx = threadIdx.x, ty = threadIdx.y;   // (32, 8)
#pragma unroll
    for (int i = 0; i < 4; ++i) {
        int c = c0 + ty + i * 8;
        tile[ty + i * 8][tx] = sf[((long)b * CC + c) * SS + s0 + tx];
    }
    __syncthreads();
#pragma unroll
    for (int i = 0; i < 4; ++i) {
        int s = s0 + ty + i * 8;
        sfT[((long)b * SS + s) * CC + c0 + tx] = tile[tx][ty + i * 8];
    }
}

// ---------------- Kernel C: weighted gather-accumulate ----------------------
__global__ __launch_bounds__(256) void accum_kernel(
    const float* __restrict__ sfT,  // [B,S,C]
    const int*   __restrict__ idx,  // [B,N,8]
    const float* __restrict__ wts,  // [B,N,8]
    float* __restrict__ out)        // [B,C,N]
{
    __shared__ float tile[256 * 17];
    const int blk = blockIdx.x;
    const int b   = blk >> 9;            // 512 blocks per batch (8192/16)
    const int n0  = (blk & 511) * 16;
    const int t   = threadIdx.x;         // channel

    float acc[16];
#pragma unroll
    for (int q = 0; q < 16; ++q) acc[q] = 0.f;

    const float* fb = sfT + (long)b * SS * CC;
    const long wbase = ((long)b * NN + n0) * KNN;

    for (int q = 0; q < 16; ++q) {
#pragma unroll
        for (int k = 0; k < KNN; ++k) {
            int   nid = idx[wbase + q * KNN + k];   // wave-uniform -> s_load
            float w   = wts[wbase + q * KNN + k];
            acc[q] += w * fb[(long)nid * CC + t];
        }
    }

#pragma unroll
    for (int q = 0; q < 16; ++q) tile[t * 17 + q] = acc[q];
    __syncthreads();

    const int j  = t & 15;
    const int cb = t >> 4;
#pragma unroll
    for (int r = 0; r < 16; ++r) {
        int c2 = r * 16 + cb;
        out[((long)b * CC + c2) * NN + n0 + j] = tile[c2 * 17 + j];
    }
}

extern "C" void kernel_launch(void* const* d_in, const int* in_sizes, int n_in,
                              void* d_out, int out_size, void* d_ws, size_t ws_size,
                              hipStream_t stream) {
    const float* xyz  = (const float*)d_in[0];   // [8,3,8192]
    const float* sxyz = (const float*)d_in[1];   // [8,3,2048]
    const float* sf   = (const float*)d_in[2];   // [8,256,2048]
    float* out = (float*)d_out;                  // [8,256,8192]

    char* ws = (char*)d_ws;
    float* sfT  = (float*)ws;                               // 16.78 MB
    int*   idxb = (int*)(ws + 16777216);                    // 2 MB
    float* wtsb = (float*)(ws + 16777216 + 2097152);        // 2 MB

    knn_kernel<<<dim3(BB * 32), dim3(256), 0, stream>>>(xyz, sxyz, idxb, wtsb);
    transpose_kernel<<<dim3(SS / 32, CC / 32, BB), dim3(32, 8), 0, stream>>>(sf, sfT);
    accum_kernel<<<dim3(BB * NN / 16), dim3(256), 0, stream>>>(sfT, idxb, wtsb, out);
}

// Round 3
// 271.355 us; speedup vs baseline: 2.4570x; 2.4570x over previous
//
#include <hip/hip_runtime.h>

#define BB 8
#define NN 8192
#define SS 2048
#define CC 256
#define KNN 8
#define TOPM 10       // per-chunk candidate margin
#define NCHUNK 4      // S split into 4 chunks of 512, one per wave
#define CH (SS / NCHUNK)
#define QPB 128       // queries per block (64 lanes x 2 queries/lane)

__device__ __forceinline__ unsigned umin32(unsigned a, unsigned b) { return a < b ? a : b; }
__device__ __forceinline__ unsigned umax32(unsigned a, unsigned b) { return a > b ? a : b; }

// ---------------- Kernel A: chunked branchless top-10 KNN + f64 re-rank -----
// Phase 1: wave w handles S-chunk w for 128 queries (2/lane). Packed u32 keys
//          (21-bit dist | 11-bit idx), branchless min/max insert network.
// Phase 2: per query, merge 4x10 candidates, f64 re-rank (u64 packed), top-8,
//          IDW weights (f32, identical to the round-2 passing epilogue).
__global__ __launch_bounds__(256) void knn_kernel(
    const float* __restrict__ xyz,   // [B,3,N]
    const float* __restrict__ sxyz,  // [B,3,S]
    int*   __restrict__ out_idx,     // [B,N,8]
    float* __restrict__ out_w)       // [B,N,8]
{
    __shared__ float4 sp[SS];                  // 32 KB
    __shared__ unsigned mbuf[QPB * NCHUNK * TOPM];  // 20 KB

    const int b   = blockIdx.x >> 6;           // 64 blocks per batch
    const int q0  = (blockIdx.x & 63) * QPB;
    const int tid = threadIdx.x;
    const int wave = tid >> 6;
    const int lane = tid & 63;

    // stage sparse points
    const float* sb = sxyz + (long)b * 3 * SS;
#pragma unroll
    for (int i = 0; i < SS / 256; ++i) {
        int s = tid + i * 256;
        sp[s] = make_float4(sb[s], sb[SS + s], sb[2 * SS + s], 0.f);
    }
    __syncthreads();

    // two queries per lane
    const float* xb = xyz + (long)b * 3 * NN;
    const int n1 = q0 + lane, n2 = q0 + 64 + lane;
    const float q1x = xb[n1], q1y = xb[NN + n1], q1z = xb[2 * NN + n1];
    const float q2x = xb[n2], q2y = xb[NN + n2], q2z = xb[2 * NN + n2];

    unsigned k1[TOPM], k2[TOPM];
#pragma unroll
    for (int j = 0; j < TOPM; ++j) { k1[j] = 0xFFFFFFFFu; k2[j] = 0xFFFFFFFFu; }

    const int sbase = wave * CH;
#pragma unroll 2
    for (int i = 0; i < CH; ++i) {
        const int s = sbase + i;
        const float4 p = sp[s];                 // wave-uniform -> broadcast
        const unsigned si = (unsigned)s;
        {
            float dx = p.x - q1x, dy = p.y - q1y, dz = p.z - q1z;
            float dist = fmaf(dx, dx, fmaf(dy, dy, dz * dz));
            unsigned c = (__float_as_uint(dist) & 0xFFFFF800u) | si;
#pragma unroll
            for (int j = TOPM - 1; j >= 1; --j)
                k1[j] = umin32(umax32(k1[j - 1], c), k1[j]);
            k1[0] = umin32(k1[0], c);
        }
        {
            float dx = p.x - q2x, dy = p.y - q2y, dz = p.z - q2z;
            float dist = fmaf(dx, dx, fmaf(dy, dy, dz * dz));
            unsigned c = (__float_as_uint(dist) & 0xFFFFF800u) | si;
#pragma unroll
            for (int j = TOPM - 1; j >= 1; --j)
                k2[j] = umin32(umax32(k2[j - 1], c), k2[j]);
            k2[0] = umin32(k2[0], c);
        }
    }

    // write partial lists: mbuf[q_local][chunk][TOPM]
    {
        unsigned* m1 = &mbuf[(lane * NCHUNK + wave) * TOPM];
        unsigned* m2 = &mbuf[((64 + lane) * NCHUNK + wave) * TOPM];
#pragma unroll
        for (int j = 0; j < TOPM; ++j) { m1[j] = k1[j]; m2[j] = k2[j]; }
    }
    __syncthreads();

    // ---- Phase 2: one thread per query ----
    if (tid < QPB) {
        const int n = q0 + tid;
        const double qx = (double)xb[n], qy = (double)xb[NN + n], qz = (double)xb[2 * NN + n];
        const unsigned* ml = &mbuf[tid * NCHUNK * TOPM];

        unsigned long long top[KNN];
#pragma unroll
        for (int j = 0; j < KNN; ++j) top[j] = ~0ull;

        for (int j = 0; j < NCHUNK * TOPM; ++j) {
            unsigned key = ml[j];
            int s = key & 0x7FF;
            float4 p = sp[s];
            double ex = (double)p.x - qx;
            double ey = (double)p.y - qy;
            double ez = (double)p.z - qz;
            double dd = ex * ex + ey * ey + ez * ez;
            unsigned long long c =
                (((unsigned long long)__double_as_longlong(dd)) & ~0x7FFull) | (unsigned long long)s;
#pragma unroll
            for (int jj = KNN - 1; jj >= 1; --jj) {
                unsigned long long hi = top[jj - 1] > c ? top[jj - 1] : c;
                top[jj] = hi < top[jj] ? hi : top[jj];
            }
            top[0] = c < top[0] ? c : top[0];
        }

        // IDW weights (f32, same as passing round-2 epilogue)
        const float fqx = xb[n], fqy = xb[NN + n], fqz = xb[2 * NN + n];
        int   id[KNN];
        float inv[KNN];
        float ssum = 0.f;
#pragma unroll
        for (int k = 0; k < KNN; ++k) {
            id[k] = (int)(top[k] & 0x7FFull);
            float4 p = sp[id[k]];
            float dx = p.x - fqx, dy = p.y - fqy, dz = p.z - fqz;
            float dv = sqrtf(dx * dx + dy * dy + dz * dz);
            dv = fmaxf(dv, 1e-10f);
            inv[k] = 1.0f / dv;
            ssum += inv[k];
        }
        const float rs = 1.0f / ssum;
        const long base = ((long)b * NN + n) * KNN;
#pragma unroll
        for (int k = 0; k < KNN; ++k) {
            out_idx[base + k] = id[k];
            out_w[base + k]   = inv[k] * rs;
        }
    }
}

// ---------------- Kernel B: sparse_feat [B,C,S] -> [B,S,C] ------------------
__global__ __launch_bounds__(256) void transpose_kernel(
    const float* __restrict__ sf,   // [B,C,S]
    float* __restrict__ sfT)        // [B,S,C]
{
    __shared__ float tile[32][33];
    const int b  = blockIdx.z;
    const int c0 = blockIdx.y * 32;
    const int s0 = blockIdx.x * 32;
    const int tx = threadIdx.x, ty = threadIdx.y;   // (32, 8)
#pragma unroll
    for (int i = 0; i < 4; ++i) {
        int c = c0 + ty + i * 8;
        tile[ty + i * 8][tx] = sf[((long)b * CC + c) * SS + s0 + tx];
    }
    __syncthreads();
#pragma unroll
    for (int i = 0; i < 4; ++i) {
        int s = s0 + ty + i * 8;
        sfT[((long)b * SS + s) * CC + c0 + tx] = tile[tx][ty + i * 8];
    }
}

// ---------------- Kernel C: weighted gather-accumulate ----------------------
__global__ __launch_bounds__(256) void accum_kernel(
    const float* __restrict__ sfT,  // [B,S,C]
    const int*   __restrict__ idx,  // [B,N,8]
    const float* __restrict__ wts,  // [B,N,8]
    float* __restrict__ out)        // [B,C,N]
{
    __shared__ float tile[256 * 17];
    const int blk = blockIdx.x;
    const int b   = blk >> 9;            // 512 blocks per batch (8192/16)
    const int n0  = (blk & 511) * 16;
    const int t   = threadIdx.x;         // channel

    float acc[16];
#pragma unroll
    for (int q = 0; q < 16; ++q) acc[q] = 0.f;

    const float* fb = sfT + (long)b * SS * CC;
    const long wbase = ((long)b * NN + n0) * KNN;

    for (int q = 0; q < 16; ++q) {
#pragma unroll
        for (int k = 0; k < KNN; ++k) {
            int   nid = idx[wbase + q * KNN + k];
            float w   = wts[wbase + q * KNN + k];
            acc[q] += w * fb[(long)nid * CC + t];
        }
    }

#pragma unroll
    for (int q = 0; q < 16; ++q) tile[t * 17 + q] = acc[q];
    __syncthreads();

    const int j  = t & 15;
    const int cb = t >> 4;
#pragma unroll
    for (int r = 0; r < 16; ++r) {
        int c2 = r * 16 + cb;
        out[((long)b * CC + c2) * NN + n0 + j] = tile[c2 * 17 + j];
    }
}

extern "C" void kernel_launch(void* const* d_in, const int* in_sizes, int n_in,
                              void* d_out, int out_size, void* d_ws, size_t ws_size,
                              hipStream_t stream) {
    const float* xyz  = (const float*)d_in[0];   // [8,3,8192]
    const float* sxyz = (const float*)d_in[1];   // [8,3,2048]
    const float* sf   = (const float*)d_in[2];   // [8,256,2048]
    float* out = (float*)d_out;                  // [8,256,8192]

    char* ws = (char*)d_ws;
    float* sfT  = (float*)ws;                               // 16.78 MB
    int*   idxb = (int*)(ws + 16777216);                    // 2 MB
    float* wtsb = (float*)(ws + 16777216 + 2097152);        // 2 MB

    knn_kernel<<<dim3(BB * NN / QPB), dim3(256), 0, stream>>>(xyz, sxyz, idxb, wtsb);
    transpose_kernel<<<dim3(SS / 32, CC / 32, BB), dim3(32, 8), 0, stream>>>(sf, sfT);
    accum_kernel<<<dim3(BB * NN / 16), dim3(256), 0, stream>>>(sfT, idxb, wtsb, out);
}

// Round 4
// 199.350 us; speedup vs baseline: 3.3444x; 1.3612x over previous
//
#include <hip/hip_runtime.h>

#define BB 8
#define NN 8192
#define SS 2048
#define CC 256
#define KNN 8
#define TOPM 10       // per-chunk candidate count (top-8 + margin)
#define NCHUNK 4      // S split into 4 chunks of 512, one per wave
#define CH (SS / NCHUNK)
#define QPB 128       // queries per block (64 lanes x 2 queries/lane)
#define MSTRIDE 41    // mbuf per-query stride (u32s): 41 mod 32 = 9 -> conflict-free

#define UMIN(a, b) __builtin_elementwise_min(a, b)
#define UMAX(a, b) __builtin_elementwise_max(a, b)
#define UMIN3(a, b, c) UMIN(UMIN(a, b), c)

// ---------------- Kernel A: chunked branchless top-10 KNN + f64 re-rank -----
__global__ __launch_bounds__(256) void knn_kernel(
    const float* __restrict__ xyz,   // [B,3,N]
    const float* __restrict__ sxyz,  // [B,3,S]
    int*   __restrict__ out_idx,     // [B,N,8]
    float* __restrict__ out_w)       // [B,N,8]
{
    __shared__ float4 sp[SS];                   // 32 KB
    __shared__ unsigned mbuf[QPB * MSTRIDE];    // 21 KB

    const int b   = blockIdx.x >> 6;            // 64 blocks per batch
    const int q0  = (blockIdx.x & 63) * QPB;
    const int tid = threadIdx.x;
    const int wave = tid >> 6;
    const int lane = tid & 63;

    const float* sb = sxyz + (long)b * 3 * SS;
#pragma unroll
    for (int i = 0; i < SS / 256; ++i) {
        int s = tid + i * 256;
        sp[s] = make_float4(sb[s], sb[SS + s], sb[2 * SS + s], 0.f);
    }
    __syncthreads();

    const float* xb = xyz + (long)b * 3 * NN;
    const int n1 = q0 + lane, n2 = q0 + 64 + lane;
    const float q1x = xb[n1], q1y = xb[NN + n1], q1z = xb[2 * NN + n1];
    const float q2x = xb[n2], q2y = xb[NN + n2], q2z = xb[2 * NN + n2];

    unsigned k1[TOPM], k2[TOPM];
#pragma unroll
    for (int j = 0; j < TOPM; ++j) { k1[j] = 0xFFFFFFFFu; k2[j] = 0xFFFFFFFFu; }

    const int sbase = wave * CH;
    for (int i = 0; i < CH; i += 2) {
        const int s0 = sbase + i;
        const float4 p0 = sp[s0];               // wave-uniform -> broadcast
        const float4 p1 = sp[s0 + 1];
        // ---- query 1: two candidates, pair-merge ----
        {
            float dx0 = p0.x - q1x, dy0 = p0.y - q1y, dz0 = p0.z - q1z;
            float dx1 = p1.x - q1x, dy1 = p1.y - q1y, dz1 = p1.z - q1z;
            float d0 = fmaf(dx0, dx0, fmaf(dy0, dy0, dz0 * dz0));
            float d1 = fmaf(dx1, dx1, fmaf(dy1, dy1, dz1 * dz1));
            unsigned c0 = (__float_as_uint(d0) & 0xFFFFF800u) | (unsigned)s0;
            unsigned c1 = (__float_as_uint(d1) & 0xFFFFF800u) | (unsigned)(s0 + 1);
            unsigned lo = UMIN(c0, c1), hi = UMAX(c0, c1);
#pragma unroll
            for (int j = TOPM - 1; j >= 2; --j)
                k1[j] = UMIN3(k1[j], UMAX(k1[j - 1], lo), UMAX(k1[j - 2], hi));
            k1[1] = UMIN3(k1[1], UMAX(k1[0], lo), hi);
            k1[0] = UMIN(k1[0], lo);
        }
        // ---- query 2 ----
        {
            float dx0 = p0.x - q2x, dy0 = p0.y - q2y, dz0 = p0.z - q2z;
            float dx1 = p1.x - q2x, dy1 = p1.y - q2y, dz1 = p1.z - q2z;
            float d0 = fmaf(dx0, dx0, fmaf(dy0, dy0, dz0 * dz0));
            float d1 = fmaf(dx1, dx1, fmaf(dy1, dy1, dz1 * dz1));
            unsigned c0 = (__float_as_uint(d0) & 0xFFFFF800u) | (unsigned)s0;
            unsigned c1 = (__float_as_uint(d1) & 0xFFFFF800u) | (unsigned)(s0 + 1);
            unsigned lo = UMIN(c0, c1), hi = UMAX(c0, c1);
#pragma unroll
            for (int j = TOPM - 1; j >= 2; --j)
                k2[j] = UMIN3(k2[j], UMAX(k2[j - 1], lo), UMAX(k2[j - 2], hi));
            k2[1] = UMIN3(k2[1], UMAX(k2[0], lo), hi);
            k2[0] = UMIN(k2[0], lo);
        }
    }

    // write partial lists: mbuf[q_local] row of 4 chunks x TOPM
    {
        unsigned* m1 = &mbuf[lane * MSTRIDE + wave * TOPM];
        unsigned* m2 = &mbuf[(64 + lane) * MSTRIDE + wave * TOPM];
#pragma unroll
        for (int j = 0; j < TOPM; ++j) { m1[j] = k1[j]; m2[j] = k2[j]; }
    }
    __syncthreads();

    // ---- Phase 2: one thread per query, f64 re-rank of 40 candidates ----
    if (tid < QPB) {
        const int n = q0 + tid;
        const double qx = (double)xb[n], qy = (double)xb[NN + n], qz = (double)xb[2 * NN + n];
        const unsigned* ml = &mbuf[tid * MSTRIDE];

        unsigned long long top[KNN];
#pragma unroll
        for (int j = 0; j < KNN; ++j) top[j] = ~0ull;

        for (int j = 0; j < NCHUNK * TOPM; ++j) {
            unsigned key = ml[j];
            int s = key & 0x7FF;
            float4 p = sp[s];
            double ex = (double)p.x - qx;
            double ey = (double)p.y - qy;
            double ez = (double)p.z - qz;
            double dd = ex * ex + ey * ey + ez * ez;
            unsigned long long c =
                (((unsigned long long)__double_as_longlong(dd)) & ~0x7FFull) | (unsigned long long)s;
#pragma unroll
            for (int jj = KNN - 1; jj >= 1; --jj)
                top[jj] = UMIN(UMAX(top[jj - 1], c), top[jj]);
            top[0] = UMIN(top[0], c);
        }

        // IDW weights (f32, identical to passing epilogue)
        const float fqx = xb[n], fqy = xb[NN + n], fqz = xb[2 * NN + n];
        int   id[KNN];
        float inv[KNN];
        float ssum = 0.f;
#pragma unroll
        for (int k = 0; k < KNN; ++k) {
            id[k] = (int)(top[k] & 0x7FFull);
            float4 p = sp[id[k]];
            float dx = p.x - fqx, dy = p.y - fqy, dz = p.z - fqz;
            float dv = sqrtf(dx * dx + dy * dy + dz * dz);
            dv = fmaxf(dv, 1e-10f);
            inv[k] = 1.0f / dv;
            ssum += inv[k];
        }
        const float rs = 1.0f / ssum;
        const long base = ((long)b * NN + n) * KNN;
#pragma unroll
        for (int k = 0; k < KNN; ++k) {
            out_idx[base + k] = id[k];
            out_w[base + k]   = inv[k] * rs;
        }
    }
}

// ---------------- Kernel B: sparse_feat [B,C,S] -> [B,S,C] ------------------
__global__ __launch_bounds__(256) void transpose_kernel(
    const float* __restrict__ sf,   // [B,C,S]
    float* __restrict__ sfT)        // [B,S,C]
{
    __shared__ float tile[32][33];
    const int b  = blockIdx.z;
    const int c0 = blockIdx.y * 32;
    const int s0 = blockIdx.x * 32;
    const int tx = threadIdx.x, ty = threadIdx.y;   // (32, 8)
#pragma unroll
    for (int i = 0; i < 4; ++i) {
        int c = c0 + ty + i * 8;
        tile[ty + i * 8][tx] = sf[((long)b * CC + c) * SS + s0 + tx];
    }
    __syncthreads();
#pragma unroll
    for (int i = 0; i < 4; ++i) {
        int s = s0 + ty + i * 8;
        sfT[((long)b * SS + s) * CC + c0 + tx] = tile[tx][ty + i * 8];
    }
}

// ---------------- Kernel C: weighted gather-accumulate (float4, XCD-pinned) -
// b = blockIdx & 7: round-robin dispatch pins each batch to one XCD so its
// 2.1 MB sfT slice stays L2-resident. One wave covers a full 256-ch row via
// float4/lane; 4 queries per wave, 16 per block.
__global__ __launch_bounds__(256) void accum_kernel(
    const float* __restrict__ sfT,  // [B,S,C]
    const int*   __restrict__ idx,  // [B,N,8]
    const float* __restrict__ wts,  // [B,N,8]
    float* __restrict__ out)        // [B,C,N]
{
    __shared__ float4 tile4[16 * 65];   // rows: q, 65 float4 (260 floats) / row
    __shared__ int    sidx[16 * 8];
    __shared__ float  swts[16 * 8];

    const int blk = blockIdx.x;
    const int b   = blk & 7;             // XCD swizzle
    const int n0  = (blk >> 3) * 16;
    const int t   = threadIdx.x;
    const int wave = t >> 6;
    const int lane = t & 63;

    if (t < 128) {
        long base = ((long)b * NN + n0) * KNN + t;
        sidx[t] = idx[base];
        swts[t] = wts[base];
    }
    __syncthreads();

    const float* fb = sfT + (long)b * SS * CC;

    float4 acc[4];
#pragma unroll
    for (int i = 0; i < 4; ++i) acc[i] = make_float4(0.f, 0.f, 0.f, 0.f);

#pragma unroll
    for (int i = 0; i < 4; ++i) {
        const int q = i * 4 + wave;
#pragma unroll
        for (int k = 0; k < KNN; ++k) {
            int   nid = sidx[q * KNN + k];           // broadcast
            float w   = swts[q * KNN + k];
            const float4 v = *(const float4*)(fb + (long)nid * CC + lane * 4);
            acc[i].x += w * v.x;
            acc[i].y += w * v.y;
            acc[i].z += w * v.z;
            acc[i].w += w * v.w;
        }
    }

#pragma unroll
    for (int i = 0; i < 4; ++i) {
        const int q = i * 4 + wave;
        tile4[q * 65 + lane] = acc[i];               // dense b128, conflict-free
    }
    __syncthreads();

    const float* tf = (const float*)tile4;
    const int j  = t & 15;                           // n offset
    const int cb = t >> 4;                           // 16 channels base
#pragma unroll
    for (int r = 0; r < 16; ++r) {
        int c2 = r * 16 + cb;
        out[((long)b * CC + c2) * NN + n0 + j] = tf[j * 260 + c2];
    }
}

extern "C" void kernel_launch(void* const* d_in, const int* in_sizes, int n_in,
                              void* d_out, int out_size, void* d_ws, size_t ws_size,
                              hipStream_t stream) {
    const float* xyz  = (const float*)d_in[0];   // [8,3,8192]
    const float* sxyz = (const float*)d_in[1];   // [8,3,2048]
    const float* sf   = (const float*)d_in[2];   // [8,256,2048]
    float* out = (float*)d_out;                  // [8,256,8192]

    char* ws = (char*)d_ws;
    float* sfT  = (float*)ws;                               // 16.78 MB
    int*   idxb = (int*)(ws + 16777216);                    // 2 MB
    float* wtsb = (float*)(ws + 16777216 + 2097152);        // 2 MB

    knn_kernel<<<dim3(BB * NN / QPB), dim3(256), 0, stream>>>(xyz, sxyz, idxb, wtsb);
    transpose_kernel<<<dim3(SS / 32, CC / 32, BB), dim3(32, 8), 0, stream>>>(sf, sfT);
    accum_kernel<<<dim3(BB * NN / 16), dim3(256), 0, stream>>>(sfT, idxb, wtsb, out);
}

// Round 5
// 192.690 us; speedup vs baseline: 3.4600x; 1.0346x over previous
//
#include <hip/hip_runtime.h>

#define BB 8
#define NN 8192
#define SS 2048
#define CC 256
#define KNN 8
#define TOPM 10       // per-chunk candidate count (top-8 + margin)
#define NCHUNK 4      // S split into 4 chunks of 512, one per wave
#define CH (SS / NCHUNK)
#define QPB 64        // queries per block (1 per lane)
#define MSTRIDE 41    // mbuf per-query stride (u32s): 41 mod 32 = 9 -> conflict-free

#define UMIN(a, b) __builtin_elementwise_min(a, b)
#define UMAX(a, b) __builtin_elementwise_max(a, b)
#define UMIN3(a, b, c) UMIN(UMIN(a, b), c)

// ---------------- Kernel A: chunked branchless top-10 KNN + f64 re-rank -----
// 1 query/lane, wave w owns S-chunk w. 4 blocks/CU (35 KB LDS) -> 4 waves/EU.
__global__ __launch_bounds__(256, 4) void knn_kernel(
    const float* __restrict__ xyz,   // [B,3,N]
    const float* __restrict__ sxyz,  // [B,3,S]
    int*   __restrict__ out_idx,     // [B,N,8]
    float* __restrict__ out_w)       // [B,N,8]
{
    __shared__ float2   sxy[SS];                // 16 KB
    __shared__ float    sz[SS];                 //  8 KB
    __shared__ unsigned mbuf[QPB * MSTRIDE];    // 10.5 KB

    const int b   = blockIdx.x >> 7;            // 128 blocks per batch
    const int q0  = (blockIdx.x & 127) * QPB;
    const int tid = threadIdx.x;
    const int wave = tid >> 6;
    const int lane = tid & 63;

    const float* sb = sxyz + (long)b * 3 * SS;
#pragma unroll
    for (int i = 0; i < SS / 256; ++i) {
        int s = tid + i * 256;
        sxy[s] = make_float2(sb[s], sb[SS + s]);
        sz[s]  = sb[2 * SS + s];
    }
    __syncthreads();

    const float* xb = xyz + (long)b * 3 * NN;
    const int n = q0 + lane;
    const float qx = xb[n], qy = xb[NN + n], qz = xb[2 * NN + n];

    unsigned k1[TOPM];
#pragma unroll
    for (int j = 0; j < TOPM; ++j) k1[j] = 0xFFFFFFFFu;

    const int sbase = wave * CH;
#pragma unroll 2
    for (int i = 0; i < CH; i += 2) {
        const int s0 = sbase + i;
        const float4 xy2 = *(const float4*)&sxy[s0];   // two points' x,y
        const float2 z2  = *(const float2*)&sz[s0];    // two points' z
        float dx0 = xy2.x - qx, dy0 = xy2.y - qy, dz0 = z2.x - qz;
        float dx1 = xy2.z - qx, dy1 = xy2.w - qy, dz1 = z2.y - qz;
        float d0 = fmaf(dx0, dx0, fmaf(dy0, dy0, dz0 * dz0));
        float d1 = fmaf(dx1, dx1, fmaf(dy1, dy1, dz1 * dz1));
        unsigned c0 = (__float_as_uint(d0) & 0xFFFFF800u) | (unsigned)s0;
        unsigned c1 = (__float_as_uint(d1) & 0xFFFFF800u) | (unsigned)(s0 + 1);
        unsigned lo = UMIN(c0, c1), hi = UMAX(c0, c1);
#pragma unroll
        for (int j = TOPM - 1; j >= 2; --j)
            k1[j] = UMIN3(k1[j], UMAX(k1[j - 1], lo), UMAX(k1[j - 2], hi));
        k1[1] = UMIN3(k1[1], UMAX(k1[0], lo), hi);
        k1[0] = UMIN(k1[0], lo);
    }

    // write partial list: mbuf[query][chunk*TOPM ...]
    {
        unsigned* m1 = &mbuf[lane * MSTRIDE + wave * TOPM];
#pragma unroll
        for (int j = 0; j < TOPM; ++j) m1[j] = k1[j];
    }
    __syncthreads();

    // ---- Phase 2: one thread per query, f64 re-rank of 40 candidates ----
    if (tid < QPB) {
        const int nq = q0 + tid;
        const double dqx = (double)xb[nq], dqy = (double)xb[NN + nq], dqz = (double)xb[2 * NN + nq];
        const unsigned* ml = &mbuf[tid * MSTRIDE];

        unsigned long long top[KNN];
#pragma unroll
        for (int j = 0; j < KNN; ++j) top[j] = ~0ull;

        for (int j = 0; j < NCHUNK * TOPM; ++j) {
            unsigned key = ml[j];
            int s = key & 0x7FF;
            float2 pxy = sxy[s];
            float  pz  = sz[s];
            double ex = (double)pxy.x - dqx;
            double ey = (double)pxy.y - dqy;
            double ez = (double)pz - dqz;
            double dd = ex * ex + ey * ey + ez * ez;
            unsigned long long c =
                (((unsigned long long)__double_as_longlong(dd)) & ~0x7FFull) | (unsigned long long)s;
#pragma unroll
            for (int jj = KNN - 1; jj >= 1; --jj)
                top[jj] = UMIN(UMAX(top[jj - 1], c), top[jj]);
            top[0] = UMIN(top[0], c);
        }

        // IDW weights (f32, identical to passing epilogue)
        const float fqx = xb[nq], fqy = xb[NN + nq], fqz = xb[2 * NN + nq];
        int   id[KNN];
        float inv[KNN];
        float ssum = 0.f;
#pragma unroll
        for (int k = 0; k < KNN; ++k) {
            id[k] = (int)(top[k] & 0x7FFull);
            float2 pxy = sxy[id[k]];
            float  pz  = sz[id[k]];
            float dx = pxy.x - fqx, dy = pxy.y - fqy, dz = pz - fqz;
            float dv = sqrtf(dx * dx + dy * dy + dz * dz);
            dv = fmaxf(dv, 1e-10f);
            inv[k] = 1.0f / dv;
            ssum += inv[k];
        }
        const float rs = 1.0f / ssum;
        const long base = ((long)b * NN + nq) * KNN;
#pragma unroll
        for (int k = 0; k < KNN; ++k) {
            out_idx[base + k] = id[k];
            out_w[base + k]   = inv[k] * rs;
        }
    }
}

// ---------------- Kernel B: sparse_feat [B,C,S] -> [B,S,C] ------------------
__global__ __launch_bounds__(256) void transpose_kernel(
    const float* __restrict__ sf,   // [B,C,S]
    float* __restrict__ sfT)        // [B,S,C]
{
    __shared__ float tile[32][33];
    const int b  = blockIdx.z;
    const int c0 = blockIdx.y * 32;
    const int s0 = blockIdx.x * 32;
    const int tx = threadIdx.x, ty = threadIdx.y;   // (32, 8)
#pragma unroll
    for (int i = 0; i < 4; ++i) {
        int c = c0 + ty + i * 8;
        tile[ty + i * 8][tx] = sf[((long)b * CC + c) * SS + s0 + tx];
    }
    __syncthreads();
#pragma unroll
    for (int i = 0; i < 4; ++i) {
        int s = s0 + ty + i * 8;
        sfT[((long)b * SS + s) * CC + c0 + tx] = tile[tx][ty + i * 8];
    }
}

// ---------------- Kernel C: weighted gather-accumulate (32 q/block) ---------
// b = blk&7 XCD pinning; wave carries 8 query-accumulators (ILP); epilogue
// stores 128 B contiguous segments (32 consecutive n per lane-group).
__global__ __launch_bounds__(256) void accum_kernel(
    const float* __restrict__ sfT,  // [B,S,C]
    const int*   __restrict__ idx,  // [B,N,8]
    const float* __restrict__ wts,  // [B,N,8]
    float* __restrict__ out)        // [B,C,N]
{
    __shared__ float4 tile4[32 * 65];   // 32 q x 260 floats = 33.3 KB
    __shared__ int    sidx[32 * 8];
    __shared__ float  swts[32 * 8];

    const int blk = blockIdx.x;
    const int b   = blk & 7;             // XCD swizzle
    const int n0  = (blk >> 3) * 32;
    const int t   = threadIdx.x;
    const int wave = t >> 6;
    const int lane = t & 63;

    {
        long base = ((long)b * NN + n0) * KNN + t;   // 256 = 32*8 values
        sidx[t] = idx[base];
        swts[t] = wts[base];
    }
    __syncthreads();

    const float* fb = sfT + (long)b * SS * CC;

    float4 acc[8];
#pragma unroll
    for (int i = 0; i < 8; ++i) acc[i] = make_float4(0.f, 0.f, 0.f, 0.f);

#pragma unroll
    for (int i = 0; i < 8; ++i) {
        const int q = wave * 8 + i;
#pragma unroll
        for (int k = 0; k < KNN; ++k) {
            int   nid = sidx[q * KNN + k];           // broadcast
            float w   = swts[q * KNN + k];
            const float4 v = *(const float4*)(fb + (long)nid * CC + lane * 4);
            acc[i].x += w * v.x;
            acc[i].y += w * v.y;
            acc[i].z += w * v.z;
            acc[i].w += w * v.w;
        }
    }

#pragma unroll
    for (int i = 0; i < 8; ++i) {
        const int q = wave * 8 + i;
        tile4[q * 65 + lane] = acc[i];               // dense b128, conflict-free
    }
    __syncthreads();

    const float* tf = (const float*)tile4;
    const int j  = t & 31;                           // n offset (32 per block)
    const int cb = t >> 5;                           // channel sub-index 0..7
#pragma unroll
    for (int r = 0; r < 32; ++r) {
        int c2 = r * 8 + cb;
        out[((long)b * CC + c2) * NN + n0 + j] = tf[j * 260 + c2];
    }
}

extern "C" void kernel_launch(void* const* d_in, const int* in_sizes, int n_in,
                              void* d_out, int out_size, void* d_ws, size_t ws_size,
                              hipStream_t stream) {
    const float* xyz  = (const float*)d_in[0];   // [8,3,8192]
    const float* sxyz = (const float*)d_in[1];   // [8,3,2048]
    const float* sf   = (const float*)d_in[2];   // [8,256,2048]
    float* out = (float*)d_out;                  // [8,256,8192]

    char* ws = (char*)d_ws;
    float* sfT  = (float*)ws;                               // 16.78 MB
    int*   idxb = (int*)(ws + 16777216);                    // 2 MB
    float* wtsb = (float*)(ws + 16777216 + 2097152);        // 2 MB

    knn_kernel<<<dim3(BB * NN / QPB), dim3(256), 0, stream>>>(xyz, sxyz, idxb, wtsb);
    transpose_kernel<<<dim3(SS / 32, CC / 32, BB), dim3(32, 8), 0, stream>>>(sf, sfT);
    accum_kernel<<<dim3(BB * NN / 32), dim3(256), 0, stream>>>(sfT, idxb, wtsb, out);
}